// Round 9
// baseline (695.289 us; speedup 1.0000x reference)
//
#include <hip/hip_runtime.h>
#include <hip/hip_fp16.h>
#include <math.h>

// 2-layer GAT, f16 pipeline. Layer-1 aggregation is channel-sliced 8-ways
// (slice = head = 16 channels); h1 stored slice-major so each slice's gather
// working set (3.2 MB) fits a 4 MB per-XCD L2; slice pinned to XCD via
// blockIdx&7. Single-pass segment softmax, packed v_pk_fma_f16 accumulation.

typedef _Float16 f16x8 __attribute__((ext_vector_type(8)));   // 8 f16 (4 VGPRs)
typedef float f32x4 __attribute__((ext_vector_type(4)));

__device__ __forceinline__ float lrelu02(float x){ return x > 0.f ? x : 0.2f*x; }

// ---------------- graph build ----------------
__global__ void k_rank(const int* __restrict__ dst, int* __restrict__ deg,
                       int* __restrict__ rank, int E){
  int i = blockIdx.x*blockDim.x + threadIdx.x;
  if (i < E) rank[i] = atomicAdd(&deg[dst[i]], 1);
}

__global__ void k_scanA(const int* __restrict__ deg, int* __restrict__ rowstart,
                        int* __restrict__ bsum, int N){
  __shared__ int lds[256];
  int t = threadIdx.x;
  int base = blockIdx.x*1024 + t*4;
  int v0 = (base+0<N)?deg[base+0]:0;
  int v1 = (base+1<N)?deg[base+1]:0;
  int v2 = (base+2<N)?deg[base+2]:0;
  int v3 = (base+3<N)?deg[base+3]:0;
  lds[t] = v0+v1+v2+v3;
  __syncthreads();
  for (int off=1; off<256; off<<=1){
    int x = (t>=off)? lds[t-off] : 0;
    __syncthreads();
    lds[t] += x;
    __syncthreads();
  }
  int run = (t==0)? 0 : lds[t-1];
  if (base+0<N) rowstart[base+0]=run;
  run += v0;
  if (base+1<N) rowstart[base+1]=run;
  run += v1;
  if (base+2<N) rowstart[base+2]=run;
  run += v2;
  if (base+3<N) rowstart[base+3]=run;
  if (t==255) bsum[blockIdx.x] = lds[255];
}

__global__ void k_scanB(int* bsum, int nblk){
  __shared__ int lds[128];
  int t = threadIdx.x;
  lds[t] = (t<nblk)? bsum[t] : 0;
  __syncthreads();
  for (int off=1; off<128; off<<=1){
    int x = (t>=off)? lds[t-off] : 0;
    __syncthreads();
    lds[t] += x;
    __syncthreads();
  }
  if (t<nblk) bsum[t] = (t==0)? 0 : lds[t-1];
}

__global__ void k_scanC(int* rowstart, const int* __restrict__ bsum, int N, int E){
  int i = blockIdx.x*blockDim.x + threadIdx.x;
  if (i < N) rowstart[i] += bsum[i>>10];
  if (i == 0) rowstart[N] = E;
}

// XCD-partitioned scatter: block b&7 owns a node range -> each csr line written
// from one XCD only (no cross-XCD partial-line write-allocate thrash).
__global__ void k_fillx(const int* __restrict__ src, const int* __restrict__ dst,
                        const int* __restrict__ rank, const int* __restrict__ rowstart,
                        int* __restrict__ csr, int E, int N){
  int xcd = blockIdx.x & 7;
  int blk = blockIdx.x >> 3;
  int nchunk = gridDim.x >> 3;
  int r0 = xcd*(N/8), r1 = (xcd==7)? N : (xcd+1)*(N/8);
  int per = (E + nchunk - 1)/nchunk;
  int lo = blk*per, hi = min(lo+per, E);
  for (int i = lo + threadIdx.x; i < hi; i += blockDim.x){
    int d = dst[i];
    if (d >= r0 && d < r1) csr[rowstart[d] + rank[i]] = src[i];
  }
}

// ---------------- weight prep: f16 weights + att-folded tiles + bias consts ----------------
__global__ void k_prep(const float* __restrict__ W1, const float* __restrict__ b1,
                       const float* __restrict__ att1,
                       const float* __restrict__ W2, const float* __restrict__ b2,
                       const float* __restrict__ att2,
                       _Float16* __restrict__ W1h, _Float16* __restrict__ W2h,
                       _Float16* __restrict__ attB1, _Float16* __restrict__ attB2,
                       float* __restrict__ consts){
  int i = blockIdx.x*blockDim.x + threadIdx.x;
  if (i < 16384){ W1h[i] = (_Float16)W1[i]; return; }
  i -= 16384;
  if (i < 6144){ int r = i >> 7; W2h[i] = (r < 40)? (_Float16)W2[i] : (_Float16)0.f; return; }
  i -= 6144;
  if (i < 2048){
    int j = i >> 7, k = i & 127;
    int h = j & 7, half = (j >> 3)*16;
    float s = 0.f;
    for (int c = 0; c < 16; ++c) s += att1[h*32 + half + c]*W1[(h*16+c)*128 + k];
    attB1[i] = (_Float16)s; return;
  }
  i -= 2048;
  if (i < 2048){
    int j = i >> 7, k = i & 127;
    float s = 0.f;
    if (j < 2){ const float* av = att2 + j*40; for (int c = 0; c < 40; ++c) s += av[c]*W2[c*128 + k]; }
    attB2[i] = (_Float16)s; return;
  }
  i -= 2048;
  if (i < 18){
    float s = 0.f;
    if (i < 8){ for (int c = 0; c < 16; ++c) s += b1[i*16+c]*att1[i*32+c]; }
    else if (i < 16){ int h = i-8; for (int c = 0; c < 16; ++c) s += b1[h*16+c]*att1[h*32+16+c]; }
    else if (i == 16){ for (int c = 0; c < 40; ++c) s += b2[c]*att2[c]; }
    else { for (int c = 0; c < 40; ++c) s += b2[c]*att2[40+c]; }
    consts[i] = s;
  }
}

// ---------------- GEMM1 (MFMA f16): slice-major h1s[8][N][16] + a1i/a1j ----------------
// 9 B-tiles: 0..7 = W1 (tile t == slice t), 8 = attB1 (a1i cols 0..7, a1j 8..15).
__global__ __launch_bounds__(256) void k_gemm1(const float* __restrict__ x,
    const _Float16* __restrict__ Wh, const _Float16* __restrict__ attB,
    const float* __restrict__ b1, const float* __restrict__ consts,
    _Float16* __restrict__ h1s, float* __restrict__ a1i, float* __restrict__ a1j, int N){
  int wid  = (blockIdx.x*256 + threadIdx.x) >> 6;
  int lane = threadIdx.x & 63;
  int m0 = wid*16;
  if (m0 >= N) return;
  int col = lane & 15, quad = lane >> 4;
  const float* xr = x + (size_t)(m0+col)*128 + quad*8;
  f32x4 acc[9];
  #pragma unroll
  for (int t=0;t<9;t++){ acc[t][0]=0.f; acc[t][1]=0.f; acc[t][2]=0.f; acc[t][3]=0.f; }
  #pragma unroll
  for (int q=0;q<4;q++){
    float4 f0 = ((const float4*)(xr + q*32))[0];
    float4 f1 = ((const float4*)(xr + q*32))[1];
    f16x8 a;
    a[0]=(_Float16)f0.x; a[1]=(_Float16)f0.y; a[2]=(_Float16)f0.z; a[3]=(_Float16)f0.w;
    a[4]=(_Float16)f1.x; a[5]=(_Float16)f1.y; a[6]=(_Float16)f1.z; a[7]=(_Float16)f1.w;
    #pragma unroll
    for (int t=0;t<8;t++){
      const f16x8* Bp = (const f16x8*)(Wh + (size_t)(t*16+col)*128 + q*32 + quad*8);
      acc[t] = __builtin_amdgcn_mfma_f32_16x16x32_f16(a, *Bp, acc[t], 0,0,0);
    }
    const f16x8* Ap = (const f16x8*)(attB + (size_t)col*128 + q*32 + quad*8);
    acc[8] = __builtin_amdgcn_mfma_f32_16x16x32_f16(a, *Ap, acc[8], 0,0,0);
  }
  size_t sstride = (size_t)N*16;
  #pragma unroll
  for (int t=0;t<8;t++){
    float bb = b1[t*16 + col];
    #pragma unroll
    for (int r=0;r<4;r++){
      h1s[(size_t)t*sstride + (size_t)(m0 + quad*4 + r)*16 + col] = (_Float16)(acc[t][r] + bb);
    }
  }
  float hb = consts[col];
  #pragma unroll
  for (int r=0;r<4;r++){
    int node = m0 + quad*4 + r;
    float v = acc[8][r] + hb;
    if (col < 8) a1i[node*8 + col] = v;
    else         a1j[node*8 + (col-8)] = v;
  }
}

// ---------------- layer-1 fused softmax+aggregate: 8 channel slices ----------------
// wave = (node, slice); slice = blockIdx&7 (XCD-pinned). Lane = (es=lane>>3 edge
// slot, cp=lane&7 channel pair). Gather target = h1s slice (3.2 MB, L2-resident).
// slice == head, so one weight per edge serves all 16 channels.
__global__ __launch_bounds__(256) void k_agg1(const unsigned* __restrict__ h1u,
    const float* __restrict__ a1i, const float* __restrict__ a1j,
    const int* __restrict__ rowstart, const int* __restrict__ csr,
    const float* __restrict__ bias, unsigned* __restrict__ x2u, int N){
  int slice = blockIdx.x & 7;
  int n = (blockIdx.x >> 3)*4 + (threadIdx.x >> 6);
  if (n >= N) return;
  int lane = threadIdx.x & 63;
  int es = lane >> 3, cp = lane & 7;
  size_t sbase = (size_t)slice * ((size_t)N*8);   // uint granularity
  int rs = rowstart[n], re = rowstart[n+1];
  float ai = a1i[(unsigned)n*8u + (unsigned)slice];
  float wself = __expf(lrelu02(ai + a1j[(unsigned)n*8u + (unsigned)slice]));
  __half2 acc; float den;
  {
    unsigned u = h1u[sbase + (unsigned)n*8u + (unsigned)cp];
    float w0 = (es==0)? wself : 0.f;
    acc = __hmul2(__float2half2_rn(w0), *(const __half2*)&u);
    den = w0;
  }
  int last = re - 1;
  unsigned csA = 0u; float ajA = 0.f;
  if (rs < re){ csA = (unsigned)csr[min(rs+es, last)]; ajA = a1j[csA*8u + (unsigned)slice]; }
  for (int e0 = rs; e0 < re; e0 += 8){
    float w = (e0+es < re)? __expf(lrelu02(ai + ajA)) : 0.f;
    unsigned u = h1u[sbase + csA*8u + (unsigned)cp];
    if (e0+8 < re){
      unsigned nc = (unsigned)csr[min(e0+8+es, last)];
      csA = nc; ajA = a1j[nc*8u + (unsigned)slice];
    }
    den += w;
    acc = __hfma2(__float2half2_rn(w), *(const __half2*)&u, acc);
  }
  float2 f = __half22float2(acc);
  float A0 = f.x, A1 = f.y;
  #pragma unroll
  for (int off = 8; off < 64; off <<= 1){
    den += __shfl_xor(den, off);
    A0  += __shfl_xor(A0, off);
    A1  += __shfl_xor(A1, off);
  }
  if (es == 0){
    float invd = 1.f/(den + 1e-16f);
    int c = slice*16 + 2*cp;
    float o0 = A0*invd + bias[c];
    float o1 = A1*invd + bias[c+1];
    o0 = (o0 > 0.f)? o0 : (__expf(o0) - 1.f);   // ELU fused
    o1 = (o1 > 0.f)? o1 : (__expf(o1) - 1.f);
    __half2 p = __floats2half2_rn(o0, o1);
    x2u[sbase + (unsigned)n*8u + (unsigned)cp] = *(unsigned*)&p;   // slice-major x2
  }
}

// ---------------- GEMM2 (MFMA f16): h2h + a2i/a2j; A read from slice-major x2 ----------------
__global__ __launch_bounds__(256) void k_gemm2(const _Float16* __restrict__ xs,
    const _Float16* __restrict__ Wh, const _Float16* __restrict__ attB,
    const float* __restrict__ b2, const float* __restrict__ consts,
    _Float16* __restrict__ h2h, float* __restrict__ a2i, float* __restrict__ a2j, int N){
  int wid  = (blockIdx.x*256 + threadIdx.x) >> 6;
  int lane = threadIdx.x & 63;
  int m0 = wid*16;
  if (m0 >= N) return;
  int col = lane & 15, quad = lane >> 4;
  size_t sstride = (size_t)N*16;
  f32x4 acc[4];
  #pragma unroll
  for (int t=0;t<4;t++){ acc[t][0]=0.f; acc[t][1]=0.f; acc[t][2]=0.f; acc[t][3]=0.f; }
  #pragma unroll
  for (int q=0;q<4;q++){
    // channels q*32 + quad*8 .. +7 live in slice 2q+(quad>>1), offset (quad&1)*8
    const f16x8* Ap = (const f16x8*)(xs + (size_t)(2*q + (quad>>1))*sstride
                                        + (size_t)(m0+col)*16 + (quad&1)*8);
    f16x8 a = *Ap;
    #pragma unroll
    for (int t=0;t<3;t++){
      const f16x8* Bp = (const f16x8*)(Wh + (size_t)(t*16+col)*128 + q*32 + quad*8);
      acc[t] = __builtin_amdgcn_mfma_f32_16x16x32_f16(a, *Bp, acc[t], 0,0,0);
    }
    const f16x8* Bp2 = (const f16x8*)(attB + (size_t)col*128 + q*32 + quad*8);
    acc[3] = __builtin_amdgcn_mfma_f32_16x16x32_f16(a, *Bp2, acc[3], 0,0,0);
  }
  #pragma unroll
  for (int t=0;t<3;t++){
    int c = t*16 + col;
    if (c < 40){
      float bb = b2[c];
      #pragma unroll
      for (int r=0;r<4;r++){
        h2h[(size_t)(m0 + quad*4 + r)*40 + c] = (_Float16)(acc[t][r] + bb);
      }
    }
  }
  if (col < 2){
    float cc = consts[16 + col];
    #pragma unroll
    for (int r=0;r<4;r++){
      int node = m0 + quad*4 + r;
      if (col == 0) a2i[node] = acc[3][r] + cc;
      else          a2j[node] = acc[3][r] + cc;
    }
  }
}

// ---------------- layer-2 fused softmax+aggregate + log_softmax ----------------
// FOUR nodes per wave; lanes ql<10 hold channel quads (uint2 of f16, hfma2).
__global__ __launch_bounds__(256) void k_agg2(const uint2* __restrict__ h2u2,
    const float* __restrict__ a2i, const float* __restrict__ a2j,
    const int* __restrict__ rowstart, const int* __restrict__ csr,
    const float* __restrict__ bias, float* __restrict__ out, int N){
  int lane = threadIdx.x & 63;
  int wid = (blockIdx.x*blockDim.x + threadIdx.x) >> 6;
  int qt = lane >> 4, ql = lane & 15;
  int n = wid*4 + qt;
  if (n >= N) return;
  bool act = ql < 10;
  unsigned cl = act ? (unsigned)ql : 0u;
  int rs = rowstart[n], re = rowstart[n+1];
  float ai = a2i[n];
  float wself = __expf(lrelu02(ai + a2j[n]));
  uint2 us = h2u2[(unsigned)n*10u + cl];
  __half2 whs = __float2half2_rn(wself);
  __half2 acc0 = __hmul2(whs, *(const __half2*)&us.x);
  __half2 acc1 = __hmul2(whs, *(const __half2*)&us.y);
  float den = wself;
  unsigned csA=0u, csB=0u; float ajA=0.f, ajB=0.f;
  if (rs < re){ csA = (unsigned)csr[rs]; ajA = a2j[csA]; }
  if (rs+1 < re){ csB = (unsigned)csr[rs+1]; ajB = a2j[csB]; }
  for (int e = rs; e < re; ++e){
    float w = __expf(lrelu02(ai + ajA));
    uint2 u = h2u2[csA*10u + cl];
    csA = csB; ajA = ajB;
    if (e+2 < re){ csB = (unsigned)csr[e+2]; ajB = a2j[csB]; }
    den += w;
    __half2 wh = __float2half2_rn(w);
    acc0 = __hfma2(wh, *(const __half2*)&u.x, acc0);
    acc1 = __hfma2(wh, *(const __half2*)&u.y, acc1);
  }
  float2 f0 = __half22float2(acc0), f1 = __half22float2(acc1);
  float invd = 1.f/(den + 1e-16f);
  const float4* b4 = (const float4*)(bias + 4*cl);
  float4 bb = b4[0];
  float v0 = f0.x*invd + bb.x, v1 = f0.y*invd + bb.y;
  float v2 = f1.x*invd + bb.z, v3 = f1.y*invd + bb.w;
  float mv = act ? fmaxf(fmaxf(v0,v1), fmaxf(v2,v3)) : -INFINITY;
  #pragma unroll
  for (int off = 1; off < 16; off <<= 1) mv = fmaxf(mv, __shfl_xor(mv, off));
  float se = act ? (__expf(v0-mv)+__expf(v1-mv)+__expf(v2-mv)+__expf(v3-mv)) : 0.f;
  #pragma unroll
  for (int off = 1; off < 16; off <<= 1) se += __shfl_xor(se, off);
  float ls = __logf(se);
  if (act){
    float4 o = make_float4(v0-mv-ls, v1-mv-ls, v2-mv-ls, v3-mv-ls);
    ((float4*)out)[(unsigned)n*10u + cl] = o;
  }
}

extern "C" void kernel_launch(void* const* d_in, const int* in_sizes, int n_in,
                              void* d_out, int out_size, void* d_ws, size_t ws_size,
                              hipStream_t stream){
  const float* x     = (const float*)d_in[0];
  const int*   ei    = (const int*)  d_in[1];
  const float* W1    = (const float*)d_in[2];
  const float* b1    = (const float*)d_in[3];
  const float* att1  = (const float*)d_in[4];
  const float* bias1 = (const float*)d_in[5];
  const float* W2    = (const float*)d_in[6];
  const float* b2    = (const float*)d_in[7];
  const float* att2  = (const float*)d_in[8];
  const float* bias2 = (const float*)d_in[9];
  int N = in_sizes[0] / 128;
  int E = in_sizes[1] / 2;
  const int* src = ei;
  const int* dst = ei + E;

  char* ws = (char*)d_ws;
  size_t off = 0;
  auto alloc = [&](size_t bytes)->char*{
    char* p = ws + off; off += (bytes + 255) & ~(size_t)255; return p;
  };
  _Float16* h1s = (_Float16*)alloc((size_t)N*128*2);   // slice-major [8][N][16]
  _Float16* x2s = (_Float16*)alloc((size_t)N*128*2);   // slice-major [8][N][16]
  _Float16* h2h = (_Float16*)alloc((size_t)N*40*2);
  float* a1i  = (float*)alloc((size_t)N*8*4);
  float* a1j  = (float*)alloc((size_t)N*8*4);
  float* a2i  = (float*)alloc((size_t)N*4);
  float* a2j  = (float*)alloc((size_t)N*4);
  _Float16* W1h   = (_Float16*)alloc(16384*2);
  _Float16* W2h   = (_Float16*)alloc(6144*2);
  _Float16* attB1 = (_Float16*)alloc(2048*2);
  _Float16* attB2 = (_Float16*)alloc(2048*2);
  float* consts = (float*)alloc(18*4);
  int*   deg  = (int*)  alloc((size_t)N*4);
  int*   rank = (int*)  alloc((size_t)E*4);
  int*   rowst= (int*)  alloc((size_t)(N+1)*4);
  int*   csr  = (int*)  alloc((size_t)E*4);
  int*   bsum = (int*)  alloc(4096);

  hipMemsetAsync(deg, 0, (size_t)N*4, stream);
  int nblk = (N + 1023)/1024;
  k_rank<<<(E+255)/256, 256, 0, stream>>>(dst, deg, rank, E);
  k_scanA<<<nblk, 256, 0, stream>>>(deg, rowst, bsum, N);
  k_scanB<<<1, 128, 0, stream>>>(bsum, nblk);
  k_scanC<<<(N+255)/256, 256, 0, stream>>>(rowst, bsum, N, E);
  k_fillx<<<1024, 256, 0, stream>>>(src, dst, rank, rowst, csr, E, N);
  k_prep<<<105, 256, 0, stream>>>(W1, b1, att1, W2, b2, att2, W1h, W2h, attB1, attB2, consts);

  int gblk = ((N+15)/16 + 3)/4;  // 4 waves/block, 16 nodes/wave
  k_gemm1<<<gblk, 256, 0, stream>>>(x, W1h, attB1, b1, consts, h1s, a1i, a1j, N);
  int ablk = ((N+3)/4)*8;        // 4 nodes/block x 8 slices; slice = blockIdx&7
  k_agg1<<<ablk, 256, 0, stream>>>((const unsigned*)h1s, a1i, a1j, rowst, csr, bias1, (unsigned*)x2s, N);

  k_gemm2<<<gblk, 256, 0, stream>>>(x2s, W2h, attB2, b2, consts, h2h, a2i, a2j, N);
  k_agg2<<<(N+15)/16, 256, 0, stream>>>((const uint2*)h2h, a2i, a2j, rowst, csr, bias2, (float*)d_out, N);
}

// Round 10
// 452.150 us; speedup vs baseline: 1.5377x; 1.5377x over previous
//
#include <hip/hip_runtime.h>
#include <hip/hip_fp16.h>
#include <math.h>

// 2-layer GAT. f16 MFMA GEMMs (fused attention-scalar B-tiles, fused fp32->f16
// A-convert), fp8-e4m3 feature storage for the edge gathers (halves gather
// traffic; attention scalars stay fp32 from the MFMA accumulator), single-pass
// segment softmax, fp32 accumulation, XCD-partitioned CSR build.
// R9 lesson: do NOT shrink gather granules below a full cache line — channel
// slicing amplified line fetches 2.5x and XCD pinning does not hold.

typedef _Float16 f16x8 __attribute__((ext_vector_type(8)));   // 8 f16 (4 VGPRs)
typedef float f32x4 __attribute__((ext_vector_type(4)));
typedef float f32x2 __attribute__((ext_vector_type(2)));

__device__ __forceinline__ float lrelu02(float x){ return x > 0.f ? x : 0.2f*x; }
__device__ __forceinline__ unsigned char f2fp8(float v){
  return (unsigned char)(__builtin_amdgcn_cvt_pk_fp8_f32(v, v, 0, false) & 0xff);
}

// ---------------- graph build ----------------
__global__ void k_count(const int* __restrict__ dst, int* __restrict__ deg, int E){
  int i = blockIdx.x*blockDim.x + threadIdx.x;
  if (i < E) atomicAdd(&deg[dst[i]], 1);
}

__global__ void k_scanA(const int* __restrict__ deg, int* __restrict__ rowstart,
                        int* __restrict__ bsum, int N){
  __shared__ int lds[256];
  int t = threadIdx.x;
  int base = blockIdx.x*1024 + t*4;
  int v0 = (base+0<N)?deg[base+0]:0;
  int v1 = (base+1<N)?deg[base+1]:0;
  int v2 = (base+2<N)?deg[base+2]:0;
  int v3 = (base+3<N)?deg[base+3]:0;
  lds[t] = v0+v1+v2+v3;
  __syncthreads();
  for (int off=1; off<256; off<<=1){
    int x = (t>=off)? lds[t-off] : 0;
    __syncthreads();
    lds[t] += x;
    __syncthreads();
  }
  int run = (t==0)? 0 : lds[t-1];
  if (base+0<N) rowstart[base+0]=run;
  run += v0;
  if (base+1<N) rowstart[base+1]=run;
  run += v1;
  if (base+2<N) rowstart[base+2]=run;
  run += v2;
  if (base+3<N) rowstart[base+3]=run;
  if (t==255) bsum[blockIdx.x] = lds[255];
}

__global__ void k_scanB(int* bsum, int nblk){
  __shared__ int lds[128];
  int t = threadIdx.x;
  lds[t] = (t<nblk)? bsum[t] : 0;
  __syncthreads();
  for (int off=1; off<128; off<<=1){
    int x = (t>=off)? lds[t-off] : 0;
    __syncthreads();
    lds[t] += x;
    __syncthreads();
  }
  if (t<nblk) bsum[t] = (t==0)? 0 : lds[t-1];
}

__global__ void k_scanC(int* rowstart, const int* __restrict__ bsum, int N, int E){
  int i = blockIdx.x*blockDim.x + threadIdx.x;
  if (i < N) rowstart[i] += bsum[i>>10];
  if (i == 0) rowstart[N] = E;
}

// XCD-partitioned scatter with in-kernel rank atomics: block b&7 owns a node
// range -> csr lines written from one XCD only; fillc atomics give the rank.
__global__ void k_fillx(const int* __restrict__ src, const int* __restrict__ dst,
                        const int* __restrict__ rowstart, int* __restrict__ fillc,
                        int* __restrict__ csr, int E, int N){
  int xcd = blockIdx.x & 7;
  int blk = blockIdx.x >> 3;
  int nchunk = gridDim.x >> 3;
  int r0 = xcd*(N/8), r1 = (xcd==7)? N : (xcd+1)*(N/8);
  int per = (E + nchunk - 1)/nchunk;
  int lo = blk*per, hi = min(lo+per, E);
  for (int i = lo + threadIdx.x; i < hi; i += blockDim.x){
    int d = dst[i];
    if (d >= r0 && d < r1){
      int pos = rowstart[d] + atomicAdd(&fillc[d], 1);
      csr[pos] = src[i];
    }
  }
}

// ---------------- weight prep: f16 weights + att-folded tiles + bias consts ----------------
__global__ void k_prep(const float* __restrict__ W1, const float* __restrict__ b1,
                       const float* __restrict__ att1,
                       const float* __restrict__ W2, const float* __restrict__ b2,
                       const float* __restrict__ att2,
                       _Float16* __restrict__ W1h, _Float16* __restrict__ W2h,
                       _Float16* __restrict__ attB1, _Float16* __restrict__ attB2,
                       float* __restrict__ consts){
  int i = blockIdx.x*blockDim.x + threadIdx.x;
  if (i < 16384){ W1h[i] = (_Float16)W1[i]; return; }
  i -= 16384;
  if (i < 6144){ int r = i >> 7; W2h[i] = (r < 40)? (_Float16)W2[i] : (_Float16)0.f; return; }
  i -= 6144;
  if (i < 2048){
    int j = i >> 7, k = i & 127;
    int h = j & 7, half = (j >> 3)*16;
    float s = 0.f;
    for (int c = 0; c < 16; ++c) s += att1[h*32 + half + c]*W1[(h*16+c)*128 + k];
    attB1[i] = (_Float16)s; return;
  }
  i -= 2048;
  if (i < 2048){
    int j = i >> 7, k = i & 127;
    float s = 0.f;
    if (j < 2){ const float* av = att2 + j*40; for (int c = 0; c < 40; ++c) s += av[c]*W2[c*128 + k]; }
    attB2[i] = (_Float16)s; return;
  }
  i -= 2048;
  if (i < 18){
    float s = 0.f;
    if (i < 8){ for (int c = 0; c < 16; ++c) s += b1[i*16+c]*att1[i*32+c]; }
    else if (i < 16){ int h = i-8; for (int c = 0; c < 16; ++c) s += b1[h*16+c]*att1[h*32+16+c]; }
    else if (i == 16){ for (int c = 0; c < 40; ++c) s += b2[c]*att2[c]; }
    else { for (int c = 0; c < 40; ++c) s += b2[c]*att2[40+c]; }
    consts[i] = s;
  }
}

// ---------------- GEMM1 (MFMA f16): h1 (fp8, row-major) + a1i/a1j (fp32) ----------------
// 9 B-tiles: 0..7 = W1 (128 oc), 8 = attB1 (a1i cols 0..7, a1j cols 8..15).
__global__ __launch_bounds__(256) void k_gemm1(const float* __restrict__ x,
    const _Float16* __restrict__ Wh, const _Float16* __restrict__ attB,
    const float* __restrict__ b1, const float* __restrict__ consts,
    unsigned char* __restrict__ h1f8, float* __restrict__ a1i, float* __restrict__ a1j, int N){
  int wid  = (blockIdx.x*256 + threadIdx.x) >> 6;
  int lane = threadIdx.x & 63;
  int m0 = wid*16;
  if (m0 >= N) return;
  int col = lane & 15, quad = lane >> 4;
  const float* xr = x + (size_t)(m0+col)*128 + quad*8;
  f32x4 acc[9];
  #pragma unroll
  for (int t=0;t<9;t++){ acc[t][0]=0.f; acc[t][1]=0.f; acc[t][2]=0.f; acc[t][3]=0.f; }
  #pragma unroll
  for (int q=0;q<4;q++){
    float4 f0 = ((const float4*)(xr + q*32))[0];
    float4 f1 = ((const float4*)(xr + q*32))[1];
    f16x8 a;
    a[0]=(_Float16)f0.x; a[1]=(_Float16)f0.y; a[2]=(_Float16)f0.z; a[3]=(_Float16)f0.w;
    a[4]=(_Float16)f1.x; a[5]=(_Float16)f1.y; a[6]=(_Float16)f1.z; a[7]=(_Float16)f1.w;
    #pragma unroll
    for (int t=0;t<8;t++){
      const f16x8* Bp = (const f16x8*)(Wh + (size_t)(t*16+col)*128 + q*32 + quad*8);
      acc[t] = __builtin_amdgcn_mfma_f32_16x16x32_f16(a, *Bp, acc[t], 0,0,0);
    }
    const f16x8* Ap = (const f16x8*)(attB + (size_t)col*128 + q*32 + quad*8);
    acc[8] = __builtin_amdgcn_mfma_f32_16x16x32_f16(a, *Ap, acc[8], 0,0,0);
  }
  #pragma unroll
  for (int t=0;t<8;t++){
    int c = t*16 + col;
    float bb = b1[c];
    #pragma unroll
    for (int r=0;r<4;r++){
      h1f8[(size_t)(m0 + quad*4 + r)*128 + c] = f2fp8(acc[t][r] + bb);
    }
  }
  float hb = consts[col];
  #pragma unroll
  for (int r=0;r<4;r++){
    int node = m0 + quad*4 + r;
    float v = acc[8][r] + hb;
    if (col < 8) a1i[node*8 + col] = v;
    else         a1j[node*8 + (col-8)] = v;
  }
}

// ---------------- layer-1 fused softmax+aggregate: quarter-wave fp8 gather ----------------
// one wave per node; quarter qt handles edge e0+qt; lane ql owns channels
// 8*ql..8*ql+7 (uint2 of fp8), head = ql>>1. fp32 accumulation.
__global__ __launch_bounds__(256) void k_agg1(const uint2* __restrict__ h1q,
    const float* __restrict__ a1i, const float* __restrict__ a1j,
    const int* __restrict__ rowstart, const int* __restrict__ csr,
    const float* __restrict__ bias, uint4* __restrict__ x2u4, int N){
  int lane = threadIdx.x & 63;
  int n = (blockIdx.x*blockDim.x + threadIdx.x) >> 6;
  if (n >= N) return;
  int ql = lane & 15, qt = lane >> 4;
  unsigned hd = (unsigned)ql >> 1;
  int rs = rowstart[n], re = rowstart[n+1];
  float ai2 = a1i[(unsigned)n*8u + hd];
  float a0=0.f,a1=0.f,a2=0.f,a3=0.f,a4=0.f,a5=0.f,a6=0.f,a7=0.f,den=0.f;
  {
    float w = (qt==0)? __expf(lrelu02(ai2 + a1j[(unsigned)n*8u + hd])) : 0.f;
    uint2 u = h1q[(unsigned)n*16u + (unsigned)ql];
    f32x2 f0 = __builtin_amdgcn_cvt_pk_f32_fp8((int)u.x, false);
    f32x2 f1 = __builtin_amdgcn_cvt_pk_f32_fp8((int)u.x, true);
    f32x2 f2 = __builtin_amdgcn_cvt_pk_f32_fp8((int)u.y, false);
    f32x2 f3 = __builtin_amdgcn_cvt_pk_f32_fp8((int)u.y, true);
    a0=w*f0[0]; a1=w*f0[1]; a2=w*f1[0]; a3=w*f1[1];
    a4=w*f2[0]; a5=w*f2[1]; a6=w*f3[0]; a7=w*f3[1];
    den = w;
  }
  int last = re - 1;
  unsigned csA=0u, csB=0u; float ajA=0.f, ajB=0.f;
  if (rs < re){ csA = (unsigned)csr[min(rs+qt, last)];   ajA = a1j[csA*8u + hd]; }
  if (rs+4 < re){ csB = (unsigned)csr[min(rs+4+qt, last)]; ajB = a1j[csB*8u + hd]; }
  int e0 = rs;
  while (e0 < re){
    { // slot A
      float w = (e0+qt < re)? __expf(lrelu02(ai2 + ajA)) : 0.f;
      uint2 u = h1q[csA*16u + (unsigned)ql];
      if (e0+8 < re){ unsigned nc=(unsigned)csr[min(e0+8+qt,last)]; csA=nc; ajA=a1j[nc*8u+hd]; }
      den += w;
      f32x2 f0 = __builtin_amdgcn_cvt_pk_f32_fp8((int)u.x, false);
      f32x2 f1 = __builtin_amdgcn_cvt_pk_f32_fp8((int)u.x, true);
      f32x2 f2 = __builtin_amdgcn_cvt_pk_f32_fp8((int)u.y, false);
      f32x2 f3 = __builtin_amdgcn_cvt_pk_f32_fp8((int)u.y, true);
      a0 += w*f0[0]; a1 += w*f0[1]; a2 += w*f1[0]; a3 += w*f1[1];
      a4 += w*f2[0]; a5 += w*f2[1]; a6 += w*f3[0]; a7 += w*f3[1];
    }
    e0 += 4;
    if (e0 >= re) break;
    { // slot B
      float w = (e0+qt < re)? __expf(lrelu02(ai2 + ajB)) : 0.f;
      uint2 u = h1q[csB*16u + (unsigned)ql];
      if (e0+8 < re){ unsigned nc=(unsigned)csr[min(e0+8+qt,last)]; csB=nc; ajB=a1j[nc*8u+hd]; }
      den += w;
      f32x2 f0 = __builtin_amdgcn_cvt_pk_f32_fp8((int)u.x, false);
      f32x2 f1 = __builtin_amdgcn_cvt_pk_f32_fp8((int)u.x, true);
      f32x2 f2 = __builtin_amdgcn_cvt_pk_f32_fp8((int)u.y, false);
      f32x2 f3 = __builtin_amdgcn_cvt_pk_f32_fp8((int)u.y, true);
      a0 += w*f0[0]; a1 += w*f0[1]; a2 += w*f1[0]; a3 += w*f1[1];
      a4 += w*f2[0]; a5 += w*f2[1]; a6 += w*f3[0]; a7 += w*f3[1];
    }
    e0 += 4;
  }
  #pragma unroll
  for (int off = 16; off < 64; off <<= 1){
    den += __shfl_xor(den, off);
    a0 += __shfl_xor(a0, off); a1 += __shfl_xor(a1, off);
    a2 += __shfl_xor(a2, off); a3 += __shfl_xor(a3, off);
    a4 += __shfl_xor(a4, off); a5 += __shfl_xor(a5, off);
    a6 += __shfl_xor(a6, off); a7 += __shfl_xor(a7, off);
  }
  if (qt == 0){
    float invd = 1.f/(den + 1e-16f);
    const float4* b4 = (const float4*)(bias + 8*ql);
    float4 bl = b4[0], bh = b4[1];
    float o0=a0*invd+bl.x, o1=a1*invd+bl.y, o2=a2*invd+bl.z, o3=a3*invd+bl.w;
    float o4=a4*invd+bh.x, o5=a5*invd+bh.y, o6=a6*invd+bh.z, o7=a7*invd+bh.w;
    o0=(o0>0.f)?o0:(__expf(o0)-1.f); o1=(o1>0.f)?o1:(__expf(o1)-1.f);
    o2=(o2>0.f)?o2:(__expf(o2)-1.f); o3=(o3>0.f)?o3:(__expf(o3)-1.f);
    o4=(o4>0.f)?o4:(__expf(o4)-1.f); o5=(o5>0.f)?o5:(__expf(o5)-1.f);
    o6=(o6>0.f)?o6:(__expf(o6)-1.f); o7=(o7>0.f)?o7:(__expf(o7)-1.f);
    __half2 p0 = __floats2half2_rn(o0,o1), p1 = __floats2half2_rn(o2,o3);
    __half2 p2 = __floats2half2_rn(o4,o5), p3 = __floats2half2_rn(o6,o7);
    uint4 o;
    o.x = *(unsigned*)&p0; o.y = *(unsigned*)&p1; o.z = *(unsigned*)&p2; o.w = *(unsigned*)&p3;
    x2u4[(unsigned)n*16u + (unsigned)ql] = o;   // x2 stays f16 (MFMA A operand)
  }
}

// ---------------- GEMM2 (MFMA f16): h2 (fp8) + a2i/a2j ----------------
__global__ __launch_bounds__(256) void k_gemm2(const _Float16* __restrict__ xh,
    const _Float16* __restrict__ Wh, const _Float16* __restrict__ attB,
    const float* __restrict__ b2, const float* __restrict__ consts,
    unsigned char* __restrict__ h2f8, float* __restrict__ a2i, float* __restrict__ a2j, int N){
  int wid  = (blockIdx.x*256 + threadIdx.x) >> 6;
  int lane = threadIdx.x & 63;
  int m0 = wid*16;
  if (m0 >= N) return;
  int col = lane & 15, quad = lane >> 4;
  const f16x8* A8 = (const f16x8*)(xh + (size_t)(m0+col)*128 + quad*8);
  f32x4 acc[4];
  #pragma unroll
  for (int t=0;t<4;t++){ acc[t][0]=0.f; acc[t][1]=0.f; acc[t][2]=0.f; acc[t][3]=0.f; }
  #pragma unroll
  for (int q=0;q<4;q++){
    f16x8 a = A8[q*4];
    #pragma unroll
    for (int t=0;t<3;t++){
      const f16x8* Bp = (const f16x8*)(Wh + (size_t)(t*16+col)*128 + q*32 + quad*8);
      acc[t] = __builtin_amdgcn_mfma_f32_16x16x32_f16(a, *Bp, acc[t], 0,0,0);
    }
    const f16x8* Bp2 = (const f16x8*)(attB + (size_t)col*128 + q*32 + quad*8);
    acc[3] = __builtin_amdgcn_mfma_f32_16x16x32_f16(a, *Bp2, acc[3], 0,0,0);
  }
  #pragma unroll
  for (int t=0;t<3;t++){
    int c = t*16 + col;
    if (c < 40){
      float bb = b2[c];
      #pragma unroll
      for (int r=0;r<4;r++){
        h2f8[(size_t)(m0 + quad*4 + r)*40 + c] = f2fp8(acc[t][r] + bb);
      }
    }
  }
  if (col < 2){
    float cc = consts[16 + col];
    #pragma unroll
    for (int r=0;r<4;r++){
      int node = m0 + quad*4 + r;
      if (col == 0) a2i[node] = acc[3][r] + cc;
      else          a2j[node] = acc[3][r] + cc;
    }
  }
}

// ---------------- layer-2 fused softmax+aggregate + log_softmax ----------------
// FOUR nodes per wave; lanes ql<10 own 4 channels (uint of fp8), fp32 accum.
__global__ __launch_bounds__(256) void k_agg2(const unsigned* __restrict__ h2u,
    const float* __restrict__ a2i, const float* __restrict__ a2j,
    const int* __restrict__ rowstart, const int* __restrict__ csr,
    const float* __restrict__ bias, float* __restrict__ out, int N){
  int lane = threadIdx.x & 63;
  int wid = (blockIdx.x*blockDim.x + threadIdx.x) >> 6;
  int qt = lane >> 4, ql = lane & 15;
  int n = wid*4 + qt;
  if (n >= N) return;
  bool act = ql < 10;
  unsigned cl = act ? (unsigned)ql : 0u;
  int rs = rowstart[n], re = rowstart[n+1];
  float ai = a2i[n];
  float wself = __expf(lrelu02(ai + a2j[n]));
  float a0,a1,a2,a3,den;
  {
    unsigned u = h2u[(unsigned)n*10u + cl];
    f32x2 f0 = __builtin_amdgcn_cvt_pk_f32_fp8((int)u, false);
    f32x2 f1 = __builtin_amdgcn_cvt_pk_f32_fp8((int)u, true);
    a0 = wself*f0[0]; a1 = wself*f0[1]; a2 = wself*f1[0]; a3 = wself*f1[1];
    den = wself;
  }
  unsigned csA=0u, csB=0u; float ajA=0.f, ajB=0.f;
  if (rs < re){ csA = (unsigned)csr[rs]; ajA = a2j[csA]; }
  if (rs+1 < re){ csB = (unsigned)csr[rs+1]; ajB = a2j[csB]; }
  for (int e = rs; e < re; ++e){
    float w = __expf(lrelu02(ai + ajA));
    unsigned u = h2u[csA*10u + cl];
    csA = csB; ajA = ajB;
    if (e+2 < re){ csB = (unsigned)csr[e+2]; ajB = a2j[csB]; }
    den += w;
    f32x2 f0 = __builtin_amdgcn_cvt_pk_f32_fp8((int)u, false);
    f32x2 f1 = __builtin_amdgcn_cvt_pk_f32_fp8((int)u, true);
    a0 += w*f0[0]; a1 += w*f0[1]; a2 += w*f1[0]; a3 += w*f1[1];
  }
  float invd = 1.f/(den + 1e-16f);
  const float4* b4 = (const float4*)(bias + 4*cl);
  float4 bb = b4[0];
  float v0 = a0*invd + bb.x, v1 = a1*invd + bb.y;
  float v2 = a2*invd + bb.z, v3 = a3*invd + bb.w;
  float mv = act ? fmaxf(fmaxf(v0,v1), fmaxf(v2,v3)) : -INFINITY;
  #pragma unroll
  for (int off = 1; off < 16; off <<= 1) mv = fmaxf(mv, __shfl_xor(mv, off));
  float se = act ? (__expf(v0-mv)+__expf(v1-mv)+__expf(v2-mv)+__expf(v3-mv)) : 0.f;
  #pragma unroll
  for (int off = 1; off < 16; off <<= 1) se += __shfl_xor(se, off);
  float ls = __logf(se);
  if (act){
    float4 o = make_float4(v0-mv-ls, v1-mv-ls, v2-mv-ls, v3-mv-ls);
    ((float4*)out)[(unsigned)n*10u + cl] = o;
  }
}

extern "C" void kernel_launch(void* const* d_in, const int* in_sizes, int n_in,
                              void* d_out, int out_size, void* d_ws, size_t ws_size,
                              hipStream_t stream){
  const float* x     = (const float*)d_in[0];
  const int*   ei    = (const int*)  d_in[1];
  const float* W1    = (const float*)d_in[2];
  const float* b1    = (const float*)d_in[3];
  const float* att1  = (const float*)d_in[4];
  const float* bias1 = (const float*)d_in[5];
  const float* W2    = (const float*)d_in[6];
  const float* b2    = (const float*)d_in[7];
  const float* att2  = (const float*)d_in[8];
  const float* bias2 = (const float*)d_in[9];
  int N = in_sizes[0] / 128;
  int E = in_sizes[1] / 2;
  const int* src = ei;
  const int* dst = ei + E;

  char* ws = (char*)d_ws;
  size_t off = 0;
  auto alloc = [&](size_t bytes)->char*{
    char* p = ws + off; off += (bytes + 255) & ~(size_t)255; return p;
  };
  unsigned char* h1f8 = (unsigned char*)alloc((size_t)N*128);   // fp8 row-major
  _Float16*      x2h  = (_Float16*)alloc((size_t)N*128*2);      // f16 (MFMA A)
  unsigned char* h2f8 = (unsigned char*)alloc((size_t)N*40);    // fp8 row-major
  float* a1i  = (float*)alloc((size_t)N*8*4);
  float* a1j  = (float*)alloc((size_t)N*8*4);
  float* a2i  = (float*)alloc((size_t)N*4);
  float* a2j  = (float*)alloc((size_t)N*4);
  _Float16* W1h   = (_Float16*)alloc(16384*2);
  _Float16* W2h   = (_Float16*)alloc(6144*2);
  _Float16* attB1 = (_Float16*)alloc(2048*2);
  _Float16* attB2 = (_Float16*)alloc(2048*2);
  float* consts = (float*)alloc(18*4);
  int*   deg  = (int*)  alloc((size_t)N*4*2);   // deg + fillc, one memset
  int*   fillc= deg + N;
  int*   rowst= (int*)  alloc((size_t)(N+1)*4);
  int*   csr  = (int*)  alloc((size_t)E*4);
  int*   bsum = (int*)  alloc(4096);

  hipMemsetAsync(deg, 0, (size_t)N*8, stream);
  int nblk = (N + 1023)/1024;
  k_count<<<(E+255)/256, 256, 0, stream>>>(dst, deg, E);
  k_scanA<<<nblk, 256, 0, stream>>>(deg, rowst, bsum, N);
  k_scanB<<<1, 128, 0, stream>>>(bsum, nblk);
  k_scanC<<<(N+255)/256, 256, 0, stream>>>(rowst, bsum, N, E);
  k_fillx<<<1024, 256, 0, stream>>>(src, dst, rowst, fillc, csr, E, N);
  k_prep<<<105, 256, 0, stream>>>(W1, b1, att1, W2, b2, att2, W1h, W2h, attB1, attB2, consts);

  int gblk = ((N+15)/16 + 3)/4;  // 4 waves/block, 16 nodes/wave
  k_gemm1<<<gblk, 256, 0, stream>>>(x, W1h, attB1, b1, consts, h1f8, a1i, a1j, N);
  k_agg1<<<(N*64+255)/256, 256, 0, stream>>>((const uint2*)h1f8, a1i, a1j, rowst, csr, bias1, (uint4*)x2h, N);

  k_gemm2<<<gblk, 256, 0, stream>>>(x2h, W2h, attB2, b2, consts, h2f8, a2i, a2j, N);
  k_agg2<<<(N+15)/16, 256, 0, stream>>>((const unsigned*)h2f8, a2i, a2j, rowst, csr, bias2, (float*)d_out, N);
}

// Round 11
// 424.600 us; speedup vs baseline: 1.6375x; 1.0649x over previous
//
#include <hip/hip_runtime.h>
#include <hip/hip_fp16.h>
#include <math.h>

// 2-layer GAT. f16 MFMA GEMMs (fused attention-scalar B-tiles, fused fp32->f16
// A-convert), fp8-e4m3 feature storage for the edge gathers, single-pass
// segment softmax, fp32 accumulation. Build: k_rank at 1 edge/thread (atomic
// return latency hidden by parallelism) + XCD-partitioned scatter-only fill.

typedef _Float16 f16x8 __attribute__((ext_vector_type(8)));   // 8 f16 (4 VGPRs)
typedef float f32x4 __attribute__((ext_vector_type(4)));
typedef float f32x2 __attribute__((ext_vector_type(2)));

__device__ __forceinline__ float lrelu02(float x){ return x > 0.f ? x : 0.2f*x; }
__device__ __forceinline__ unsigned char f2fp8(float v){
  return (unsigned char)(__builtin_amdgcn_cvt_pk_fp8_f32(v, v, 0, false) & 0xff);
}

// ---------------- graph build ----------------
// rank[i] = position of edge i within its dst bucket; deg accumulates counts.
// ONE edge per thread: atomic-with-return latency is hidden by 6250 blocks.
__global__ void k_rank(const int* __restrict__ dst, int* __restrict__ deg,
                       int* __restrict__ rank, int E){
  int i = blockIdx.x*blockDim.x + threadIdx.x;
  if (i < E) rank[i] = atomicAdd(&deg[dst[i]], 1);
}

__global__ void k_scanA(const int* __restrict__ deg, int* __restrict__ rowstart,
                        int* __restrict__ bsum, int N){
  __shared__ int lds[256];
  int t = threadIdx.x;
  int base = blockIdx.x*1024 + t*4;
  int v0 = (base+0<N)?deg[base+0]:0;
  int v1 = (base+1<N)?deg[base+1]:0;
  int v2 = (base+2<N)?deg[base+2]:0;
  int v3 = (base+3<N)?deg[base+3]:0;
  lds[t] = v0+v1+v2+v3;
  __syncthreads();
  for (int off=1; off<256; off<<=1){
    int x = (t>=off)? lds[t-off] : 0;
    __syncthreads();
    lds[t] += x;
    __syncthreads();
  }
  int run = (t==0)? 0 : lds[t-1];
  if (base+0<N) rowstart[base+0]=run;
  run += v0;
  if (base+1<N) rowstart[base+1]=run;
  run += v1;
  if (base+2<N) rowstart[base+2]=run;
  run += v2;
  if (base+3<N) rowstart[base+3]=run;
  if (t==255) bsum[blockIdx.x] = lds[255];
}

__global__ void k_scanB(int* bsum, int nblk){
  __shared__ int lds[128];
  int t = threadIdx.x;
  lds[t] = (t<nblk)? bsum[t] : 0;
  __syncthreads();
  for (int off=1; off<128; off<<=1){
    int x = (t>=off)? lds[t-off] : 0;
    __syncthreads();
    lds[t] += x;
    __syncthreads();
  }
  if (t<nblk) bsum[t] = (t==0)? 0 : lds[t-1];
}

__global__ void k_scanC(int* rowstart, const int* __restrict__ bsum, int N, int E){
  int i = blockIdx.x*blockDim.x + threadIdx.x;
  if (i < N) rowstart[i] += bsum[i>>10];
  if (i == 0) rowstart[N] = E;
}

// Scatter-only, XCD-partitioned: block b&7 owns a node range -> each csr line
// written from one XCD only (no cross-XCD partial-line write-allocate thrash).
__global__ void k_fillx(const int* __restrict__ src, const int* __restrict__ dst,
                        const int* __restrict__ rank, const int* __restrict__ rowstart,
                        int* __restrict__ csr, int E, int N){
  int xcd = blockIdx.x & 7;
  int blk = blockIdx.x >> 3;
  int nchunk = gridDim.x >> 3;
  int r0 = xcd*(N/8), r1 = (xcd==7)? N : (xcd+1)*(N/8);
  int per = (E + nchunk - 1)/nchunk;
  int lo = blk*per, hi = min(lo+per, E);
  for (int i = lo + threadIdx.x; i < hi; i += blockDim.x){
    int d = dst[i];
    if (d >= r0 && d < r1) csr[rowstart[d] + rank[i]] = src[i];
  }
}

// ---------------- weight prep: f16 weights + att-folded tiles + bias consts ----------------
__global__ void k_prep(const float* __restrict__ W1, const float* __restrict__ b1,
                       const float* __restrict__ att1,
                       const float* __restrict__ W2, const float* __restrict__ b2,
                       const float* __restrict__ att2,
                       _Float16* __restrict__ W1h, _Float16* __restrict__ W2h,
                       _Float16* __restrict__ attB1, _Float16* __restrict__ attB2,
                       float* __restrict__ consts){
  int i = blockIdx.x*blockDim.x + threadIdx.x;
  if (i < 16384){ W1h[i] = (_Float16)W1[i]; return; }
  i -= 16384;
  if (i < 6144){ int r = i >> 7; W2h[i] = (r < 40)? (_Float16)W2[i] : (_Float16)0.f; return; }
  i -= 6144;
  if (i < 2048){
    int j = i >> 7, k = i & 127;
    int h = j & 7, half = (j >> 3)*16;
    float s = 0.f;
    for (int c = 0; c < 16; ++c) s += att1[h*32 + half + c]*W1[(h*16+c)*128 + k];
    attB1[i] = (_Float16)s; return;
  }
  i -= 2048;
  if (i < 2048){
    int j = i >> 7, k = i & 127;
    float s = 0.f;
    if (j < 2){ const float* av = att2 + j*40; for (int c = 0; c < 40; ++c) s += av[c]*W2[c*128 + k]; }
    attB2[i] = (_Float16)s; return;
  }
  i -= 2048;
  if (i < 18){
    float s = 0.f;
    if (i < 8){ for (int c = 0; c < 16; ++c) s += b1[i*16+c]*att1[i*32+c]; }
    else if (i < 16){ int h = i-8; for (int c = 0; c < 16; ++c) s += b1[h*16+c]*att1[h*32+16+c]; }
    else if (i == 16){ for (int c = 0; c < 40; ++c) s += b2[c]*att2[c]; }
    else { for (int c = 0; c < 40; ++c) s += b2[c]*att2[40+c]; }
    consts[i] = s;
  }
}

// ---------------- GEMM1 (MFMA f16): h1 (fp8, row-major) + a1i/a1j (fp32) ----------------
__global__ __launch_bounds__(256) void k_gemm1(const float* __restrict__ x,
    const _Float16* __restrict__ Wh, const _Float16* __restrict__ attB,
    const float* __restrict__ b1, const float* __restrict__ consts,
    unsigned char* __restrict__ h1f8, float* __restrict__ a1i, float* __restrict__ a1j, int N){
  int wid  = (blockIdx.x*256 + threadIdx.x) >> 6;
  int lane = threadIdx.x & 63;
  int m0 = wid*16;
  if (m0 >= N) return;
  int col = lane & 15, quad = lane >> 4;
  const float* xr = x + (size_t)(m0+col)*128 + quad*8;
  f32x4 acc[9];
  #pragma unroll
  for (int t=0;t<9;t++){ acc[t][0]=0.f; acc[t][1]=0.f; acc[t][2]=0.f; acc[t][3]=0.f; }
  #pragma unroll
  for (int q=0;q<4;q++){
    float4 f0 = ((const float4*)(xr + q*32))[0];
    float4 f1 = ((const float4*)(xr + q*32))[1];
    f16x8 a;
    a[0]=(_Float16)f0.x; a[1]=(_Float16)f0.y; a[2]=(_Float16)f0.z; a[3]=(_Float16)f0.w;
    a[4]=(_Float16)f1.x; a[5]=(_Float16)f1.y; a[6]=(_Float16)f1.z; a[7]=(_Float16)f1.w;
    #pragma unroll
    for (int t=0;t<8;t++){
      const f16x8* Bp = (const f16x8*)(Wh + (size_t)(t*16+col)*128 + q*32 + quad*8);
      acc[t] = __builtin_amdgcn_mfma_f32_16x16x32_f16(a, *Bp, acc[t], 0,0,0);
    }
    const f16x8* Ap = (const f16x8*)(attB + (size_t)col*128 + q*32 + quad*8);
    acc[8] = __builtin_amdgcn_mfma_f32_16x16x32_f16(a, *Ap, acc[8], 0,0,0);
  }
  #pragma unroll
  for (int t=0;t<8;t++){
    int c = t*16 + col;
    float bb = b1[c];
    #pragma unroll
    for (int r=0;r<4;r++){
      h1f8[(size_t)(m0 + quad*4 + r)*128 + c] = f2fp8(acc[t][r] + bb);
    }
  }
  float hb = consts[col];
  #pragma unroll
  for (int r=0;r<4;r++){
    int node = m0 + quad*4 + r;
    float v = acc[8][r] + hb;
    if (col < 8) a1i[node*8 + col] = v;
    else         a1j[node*8 + (col-8)] = v;
  }
}

// ---------------- layer-1 fused softmax+aggregate: quarter-wave fp8 gather ----------------
// one wave per node; quarter qt handles edge e0+qt; lane ql owns channels
// 8*ql..8*ql+7 (uint2 of fp8), head = ql>>1. 3-slot pipeline (12 edges in flight).
__global__ __launch_bounds__(256) void k_agg1(const uint2* __restrict__ h1q,
    const float* __restrict__ a1i, const float* __restrict__ a1j,
    const int* __restrict__ rowstart, const int* __restrict__ csr,
    const float* __restrict__ bias, uint4* __restrict__ x2u4, int N){
  int lane = threadIdx.x & 63;
  int n = (blockIdx.x*blockDim.x + threadIdx.x) >> 6;
  if (n >= N) return;
  int ql = lane & 15, qt = lane >> 4;
  unsigned hd = (unsigned)ql >> 1;
  int rs = rowstart[n], re = rowstart[n+1];
  float ai2 = a1i[(unsigned)n*8u + hd];
  float a0=0.f,a1=0.f,a2=0.f,a3=0.f,a4=0.f,a5=0.f,a6=0.f,a7=0.f,den=0.f;
  {
    float w = (qt==0)? __expf(lrelu02(ai2 + a1j[(unsigned)n*8u + hd])) : 0.f;
    uint2 u = h1q[(unsigned)n*16u + (unsigned)ql];
    f32x2 f0 = __builtin_amdgcn_cvt_pk_f32_fp8((int)u.x, false);
    f32x2 f1 = __builtin_amdgcn_cvt_pk_f32_fp8((int)u.x, true);
    f32x2 f2 = __builtin_amdgcn_cvt_pk_f32_fp8((int)u.y, false);
    f32x2 f3 = __builtin_amdgcn_cvt_pk_f32_fp8((int)u.y, true);
    a0=w*f0[0]; a1=w*f0[1]; a2=w*f1[0]; a3=w*f1[1];
    a4=w*f2[0]; a5=w*f2[1]; a6=w*f3[0]; a7=w*f3[1];
    den = w;
  }
  int last = re - 1;
  unsigned cs[3]; float aj[3];
  #pragma unroll
  for (int s=0;s<3;s++){
    if (rs + 4*s < re){
      cs[s] = (unsigned)csr[min(rs+4*s+qt, last)];
      aj[s] = a1j[cs[s]*8u + hd];
    } else { cs[s] = 0u; aj[s] = 0.f; }
  }
  int e0 = rs;
  int sl = 0;
  while (e0 < re){
    float w = (e0+qt < re)? __expf(lrelu02(ai2 + aj[sl])) : 0.f;
    uint2 u = h1q[cs[sl]*16u + (unsigned)ql];
    if (e0+12 < re){
      unsigned nc = (unsigned)csr[min(e0+12+qt, last)];
      cs[sl] = nc; aj[sl] = a1j[nc*8u + hd];
    }
    den += w;
    f32x2 f0 = __builtin_amdgcn_cvt_pk_f32_fp8((int)u.x, false);
    f32x2 f1 = __builtin_amdgcn_cvt_pk_f32_fp8((int)u.x, true);
    f32x2 f2 = __builtin_amdgcn_cvt_pk_f32_fp8((int)u.y, false);
    f32x2 f3 = __builtin_amdgcn_cvt_pk_f32_fp8((int)u.y, true);
    a0 += w*f0[0]; a1 += w*f0[1]; a2 += w*f1[0]; a3 += w*f1[1];
    a4 += w*f2[0]; a5 += w*f2[1]; a6 += w*f3[0]; a7 += w*f3[1];
    e0 += 4;
    sl = (sl == 2)? 0 : sl+1;
  }
  #pragma unroll
  for (int off = 16; off < 64; off <<= 1){
    den += __shfl_xor(den, off);
    a0 += __shfl_xor(a0, off); a1 += __shfl_xor(a1, off);
    a2 += __shfl_xor(a2, off); a3 += __shfl_xor(a3, off);
    a4 += __shfl_xor(a4, off); a5 += __shfl_xor(a5, off);
    a6 += __shfl_xor(a6, off); a7 += __shfl_xor(a7, off);
  }
  if (qt == 0){
    float invd = 1.f/(den + 1e-16f);
    const float4* b4 = (const float4*)(bias + 8*ql);
    float4 bl = b4[0], bh = b4[1];
    float o0=a0*invd+bl.x, o1=a1*invd+bl.y, o2=a2*invd+bl.z, o3=a3*invd+bl.w;
    float o4=a4*invd+bh.x, o5=a5*invd+bh.y, o6=a6*invd+bh.z, o7=a7*invd+bh.w;
    o0=(o0>0.f)?o0:(__expf(o0)-1.f); o1=(o1>0.f)?o1:(__expf(o1)-1.f);
    o2=(o2>0.f)?o2:(__expf(o2)-1.f); o3=(o3>0.f)?o3:(__expf(o3)-1.f);
    o4=(o4>0.f)?o4:(__expf(o4)-1.f); o5=(o5>0.f)?o5:(__expf(o5)-1.f);
    o6=(o6>0.f)?o6:(__expf(o6)-1.f); o7=(o7>0.f)?o7:(__expf(o7)-1.f);
    __half2 p0 = __floats2half2_rn(o0,o1), p1 = __floats2half2_rn(o2,o3);
    __half2 p2 = __floats2half2_rn(o4,o5), p3 = __floats2half2_rn(o6,o7);
    uint4 o;
    o.x = *(unsigned*)&p0; o.y = *(unsigned*)&p1; o.z = *(unsigned*)&p2; o.w = *(unsigned*)&p3;
    x2u4[(unsigned)n*16u + (unsigned)ql] = o;   // x2 stays f16 (MFMA A operand)
  }
}

// ---------------- GEMM2 (MFMA f16): h2 (fp8) + a2i/a2j ----------------
__global__ __launch_bounds__(256) void k_gemm2(const _Float16* __restrict__ xh,
    const _Float16* __restrict__ Wh, const _Float16* __restrict__ attB,
    const float* __restrict__ b2, const float* __restrict__ consts,
    unsigned char* __restrict__ h2f8, float* __restrict__ a2i, float* __restrict__ a2j, int N){
  int wid  = (blockIdx.x*256 + threadIdx.x) >> 6;
  int lane = threadIdx.x & 63;
  int m0 = wid*16;
  if (m0 >= N) return;
  int col = lane & 15, quad = lane >> 4;
  const f16x8* A8 = (const f16x8*)(xh + (size_t)(m0+col)*128 + quad*8);
  f32x4 acc[4];
  #pragma unroll
  for (int t=0;t<4;t++){ acc[t][0]=0.f; acc[t][1]=0.f; acc[t][2]=0.f; acc[t][3]=0.f; }
  #pragma unroll
  for (int q=0;q<4;q++){
    f16x8 a = A8[q*4];
    #pragma unroll
    for (int t=0;t<3;t++){
      const f16x8* Bp = (const f16x8*)(Wh + (size_t)(t*16+col)*128 + q*32 + quad*8);
      acc[t] = __builtin_amdgcn_mfma_f32_16x16x32_f16(a, *Bp, acc[t], 0,0,0);
    }
    const f16x8* Bp2 = (const f16x8*)(attB + (size_t)col*128 + q*32 + quad*8);
    acc[3] = __builtin_amdgcn_mfma_f32_16x16x32_f16(a, *Bp2, acc[3], 0,0,0);
  }
  #pragma unroll
  for (int t=0;t<3;t++){
    int c = t*16 + col;
    if (c < 40){
      float bb = b2[c];
      #pragma unroll
      for (int r=0;r<4;r++){
        h2f8[(size_t)(m0 + quad*4 + r)*40 + c] = f2fp8(acc[t][r] + bb);
      }
    }
  }
  if (col < 2){
    float cc = consts[16 + col];
    #pragma unroll
    for (int r=0;r<4;r++){
      int node = m0 + quad*4 + r;
      if (col == 0) a2i[node] = acc[3][r] + cc;
      else          a2j[node] = acc[3][r] + cc;
    }
  }
}

// ---------------- layer-2 fused softmax+aggregate + log_softmax ----------------
// FOUR nodes per wave; lanes ql<10 own 4 channels (uint of fp8), fp32 accum.
__global__ __launch_bounds__(256) void k_agg2(const unsigned* __restrict__ h2u,
    const float* __restrict__ a2i, const float* __restrict__ a2j,
    const int* __restrict__ rowstart, const int* __restrict__ csr,
    const float* __restrict__ bias, float* __restrict__ out, int N){
  int lane = threadIdx.x & 63;
  int wid = (blockIdx.x*blockDim.x + threadIdx.x) >> 6;
  int qt = lane >> 4, ql = lane & 15;
  int n = wid*4 + qt;
  if (n >= N) return;
  bool act = ql < 10;
  unsigned cl = act ? (unsigned)ql : 0u;
  int rs = rowstart[n], re = rowstart[n+1];
  float ai = a2i[n];
  float wself = __expf(lrelu02(ai + a2j[n]));
  float a0,a1,a2,a3,den;
  {
    unsigned u = h2u[(unsigned)n*10u + cl];
    f32x2 f0 = __builtin_amdgcn_cvt_pk_f32_fp8((int)u, false);
    f32x2 f1 = __builtin_amdgcn_cvt_pk_f32_fp8((int)u, true);
    a0 = wself*f0[0]; a1 = wself*f0[1]; a2 = wself*f1[0]; a3 = wself*f1[1];
    den = wself;
  }
  unsigned csA=0u, csB=0u; float ajA=0.f, ajB=0.f;
  if (rs < re){ csA = (unsigned)csr[rs]; ajA = a2j[csA]; }
  if (rs+1 < re){ csB = (unsigned)csr[rs+1]; ajB = a2j[csB]; }
  for (int e = rs; e < re; ++e){
    float w = __expf(lrelu02(ai + ajA));
    unsigned u = h2u[csA*10u + cl];
    csA = csB; ajA = ajB;
    if (e+2 < re){ csB = (unsigned)csr[e+2]; ajB = a2j[csB]; }
    den += w;
    f32x2 f0 = __builtin_amdgcn_cvt_pk_f32_fp8((int)u, false);
    f32x2 f1 = __builtin_amdgcn_cvt_pk_f32_fp8((int)u, true);
    a0 += w*f0[0]; a1 += w*f0[1]; a2 += w*f1[0]; a3 += w*f1[1];
  }
  float invd = 1.f/(den + 1e-16f);
  const float4* b4 = (const float4*)(bias + 4*cl);
  float4 bb = b4[0];
  float v0 = a0*invd + bb.x, v1 = a1*invd + bb.y;
  float v2 = a2*invd + bb.z, v3 = a3*invd + bb.w;
  float mv = act ? fmaxf(fmaxf(v0,v1), fmaxf(v2,v3)) : -INFINITY;
  #pragma unroll
  for (int off = 1; off < 16; off <<= 1) mv = fmaxf(mv, __shfl_xor(mv, off));
  float se = act ? (__expf(v0-mv)+__expf(v1-mv)+__expf(v2-mv)+__expf(v3-mv)) : 0.f;
  #pragma unroll
  for (int off = 1; off < 16; off <<= 1) se += __shfl_xor(se, off);
  float ls = __logf(se);
  if (act){
    float4 o = make_float4(v0-mv-ls, v1-mv-ls, v2-mv-ls, v3-mv-ls);
    ((float4*)out)[(unsigned)n*10u + cl] = o;
  }
}

extern "C" void kernel_launch(void* const* d_in, const int* in_sizes, int n_in,
                              void* d_out, int out_size, void* d_ws, size_t ws_size,
                              hipStream_t stream){
  const float* x     = (const float*)d_in[0];
  const int*   ei    = (const int*)  d_in[1];
  const float* W1    = (const float*)d_in[2];
  const float* b1    = (const float*)d_in[3];
  const float* att1  = (const float*)d_in[4];
  const float* bias1 = (const float*)d_in[5];
  const float* W2    = (const float*)d_in[6];
  const float* b2    = (const float*)d_in[7];
  const float* att2  = (const float*)d_in[8];
  const float* bias2 = (const float*)d_in[9];
  int N = in_sizes[0] / 128;
  int E = in_sizes[1] / 2;
  const int* src = ei;
  const int* dst = ei + E;

  char* ws = (char*)d_ws;
  size_t off = 0;
  auto alloc = [&](size_t bytes)->char*{
    char* p = ws + off; off += (bytes + 255) & ~(size_t)255; return p;
  };
  unsigned char* h1f8 = (unsigned char*)alloc((size_t)N*128);   // fp8 row-major
  _Float16*      x2h  = (_Float16*)alloc((size_t)N*128*2);      // f16 (MFMA A)
  unsigned char* h2f8 = (unsigned char*)alloc((size_t)N*40);    // fp8 row-major
  float* a1i  = (float*)alloc((size_t)N*8*4);
  float* a1j  = (float*)alloc((size_t)N*8*4);
  float* a2i  = (float*)alloc((size_t)N*4);
  float* a2j  = (float*)alloc((size_t)N*4);
  _Float16* W1h   = (_Float16*)alloc(16384*2);
  _Float16* W2h   = (_Float16*)alloc(6144*2);
  _Float16* attB1 = (_Float16*)alloc(2048*2);
  _Float16* attB2 = (_Float16*)alloc(2048*2);
  float* consts = (float*)alloc(18*4);
  int*   deg  = (int*)  alloc((size_t)N*4);
  int*   rank = (int*)  alloc((size_t)E*4);
  int*   rowst= (int*)  alloc((size_t)(N+1)*4);
  int*   csr  = (int*)  alloc((size_t)E*4);
  int*   bsum = (int*)  alloc(4096);

  hipMemsetAsync(deg, 0, (size_t)N*4, stream);
  int nblk = (N + 1023)/1024;
  k_rank<<<(E+255)/256, 256, 0, stream>>>(dst, deg, rank, E);
  k_scanA<<<nblk, 256, 0, stream>>>(deg, rowst, bsum, N);
  k_scanB<<<1, 128, 0, stream>>>(bsum, nblk);
  k_scanC<<<(N+255)/256, 256, 0, stream>>>(rowst, bsum, N, E);
  k_fillx<<<1024, 256, 0, stream>>>(src, dst, rank, rowst, csr, E, N);
  k_prep<<<105, 256, 0, stream>>>(W1, b1, att1, W2, b2, att2, W1h, W2h, attB1, attB2, consts);

  int gblk = ((N+15)/16 + 3)/4;  // 4 waves/block, 16 nodes/wave
  k_gemm1<<<gblk, 256, 0, stream>>>(x, W1h, attB1, b1, consts, h1f8, a1i, a1j, N);
  k_agg1<<<(N*64+255)/256, 256, 0, stream>>>((const uint2*)h1f8, a1i, a1j, rowst, csr, bias1, (uint4*)x2h, N);

  k_gemm2<<<gblk, 256, 0, stream>>>(x2h, W2h, attB2, b2, consts, h2f8, a2i, a2j, N);
  k_agg2<<<(N+15)/16, 256, 0, stream>>>((const unsigned*)h2f8, a2i, a2j, rowst, csr, bias2, (float*)d_out, N);
}

// Round 12
// 386.227 us; speedup vs baseline: 1.8002x; 1.0994x over previous
//
#include <hip/hip_runtime.h>
#include <hip/hip_fp16.h>
#include <math.h>

// 2-layer GAT. f16 MFMA GEMMs (fused attention-scalar B-tiles, fused fp32->f16
// A-convert), fp8-e4m3 feature storage for the edge gathers, single-pass
// segment softmax, fp32 accumulation. Aggregations use a statically-unrolled
// 4-stage pipeline: cs/aj ring 16 edges ahead, feature gather prefetched 8
// edges ahead via a cs register loaded 2 stages prior (no dependent stall,
// no runtime-indexed register arrays — R11 lesson).

typedef _Float16 f16x8 __attribute__((ext_vector_type(8)));   // 8 f16 (4 VGPRs)
typedef float f32x4 __attribute__((ext_vector_type(4)));
typedef float f32x2 __attribute__((ext_vector_type(2)));

__device__ __forceinline__ float lrelu02(float x){ return x > 0.f ? x : 0.2f*x; }
__device__ __forceinline__ unsigned char f2fp8(float v){
  return (unsigned char)(__builtin_amdgcn_cvt_pk_fp8_f32(v, v, 0, false) & 0xff);
}

// ---------------- graph build ----------------
// ONE edge per thread: atomic-with-return latency hidden by parallelism (R10 lesson).
__global__ void k_rank(const int* __restrict__ dst, int* __restrict__ deg,
                       int* __restrict__ rank, int E){
  int i = blockIdx.x*blockDim.x + threadIdx.x;
  if (i < E) rank[i] = atomicAdd(&deg[dst[i]], 1);
}

__global__ void k_scanA(const int* __restrict__ deg, int* __restrict__ rowstart,
                        int* __restrict__ bsum, int N){
  __shared__ int lds[256];
  int t = threadIdx.x;
  int base = blockIdx.x*1024 + t*4;
  int v0 = (base+0<N)?deg[base+0]:0;
  int v1 = (base+1<N)?deg[base+1]:0;
  int v2 = (base+2<N)?deg[base+2]:0;
  int v3 = (base+3<N)?deg[base+3]:0;
  lds[t] = v0+v1+v2+v3;
  __syncthreads();
  for (int off=1; off<256; off<<=1){
    int x = (t>=off)? lds[t-off] : 0;
    __syncthreads();
    lds[t] += x;
    __syncthreads();
  }
  int run = (t==0)? 0 : lds[t-1];
  if (base+0<N) rowstart[base+0]=run;
  run += v0;
  if (base+1<N) rowstart[base+1]=run;
  run += v1;
  if (base+2<N) rowstart[base+2]=run;
  run += v2;
  if (base+3<N) rowstart[base+3]=run;
  if (t==255) bsum[blockIdx.x] = lds[255];
}

__global__ void k_scanB(int* bsum, int nblk){
  __shared__ int lds[128];
  int t = threadIdx.x;
  lds[t] = (t<nblk)? bsum[t] : 0;
  __syncthreads();
  for (int off=1; off<128; off<<=1){
    int x = (t>=off)? lds[t-off] : 0;
    __syncthreads();
    lds[t] += x;
    __syncthreads();
  }
  if (t<nblk) bsum[t] = (t==0)? 0 : lds[t-1];
}

__global__ void k_scanC(int* rowstart, const int* __restrict__ bsum, int N, int E){
  int i = blockIdx.x*blockDim.x + threadIdx.x;
  if (i < N) rowstart[i] += bsum[i>>10];
  if (i == 0) rowstart[N] = E;
}

// Scatter-only, XCD-partitioned: block b&7 owns a node range -> each csr line
// written from one XCD only (no cross-XCD partial-line write-allocate thrash).
__global__ void k_fillx(const int* __restrict__ src, const int* __restrict__ dst,
                        const int* __restrict__ rank, const int* __restrict__ rowstart,
                        int* __restrict__ csr, int E, int N){
  int xcd = blockIdx.x & 7;
  int blk = blockIdx.x >> 3;
  int nchunk = gridDim.x >> 3;
  int r0 = xcd*(N/8), r1 = (xcd==7)? N : (xcd+1)*(N/8);
  int per = (E + nchunk - 1)/nchunk;
  int lo = blk*per, hi = min(lo+per, E);
  for (int i = lo + threadIdx.x; i < hi; i += blockDim.x){
    int d = dst[i];
    if (d >= r0 && d < r1) csr[rowstart[d] + rank[i]] = src[i];
  }
}

// ---------------- weight prep: f16 weights + att-folded tiles + bias consts ----------------
__global__ void k_prep(const float* __restrict__ W1, const float* __restrict__ b1,
                       const float* __restrict__ att1,
                       const float* __restrict__ W2, const float* __restrict__ b2,
                       const float* __restrict__ att2,
                       _Float16* __restrict__ W1h, _Float16* __restrict__ W2h,
                       _Float16* __restrict__ attB1, _Float16* __restrict__ attB2,
                       float* __restrict__ consts){
  int i = blockIdx.x*blockDim.x + threadIdx.x;
  if (i < 16384){ W1h[i] = (_Float16)W1[i]; return; }
  i -= 16384;
  if (i < 6144){ int r = i >> 7; W2h[i] = (r < 40)? (_Float16)W2[i] : (_Float16)0.f; return; }
  i -= 6144;
  if (i < 2048){
    int j = i >> 7, k = i & 127;
    int h = j & 7, half = (j >> 3)*16;
    float s = 0.f;
    for (int c = 0; c < 16; ++c) s += att1[h*32 + half + c]*W1[(h*16+c)*128 + k];
    attB1[i] = (_Float16)s; return;
  }
  i -= 2048;
  if (i < 2048){
    int j = i >> 7, k = i & 127;
    float s = 0.f;
    if (j < 2){ const float* av = att2 + j*40; for (int c = 0; c < 40; ++c) s += av[c]*W2[c*128 + k]; }
    attB2[i] = (_Float16)s; return;
  }
  i -= 2048;
  if (i < 18){
    float s = 0.f;
    if (i < 8){ for (int c = 0; c < 16; ++c) s += b1[i*16+c]*att1[i*32+c]; }
    else if (i < 16){ int h = i-8; for (int c = 0; c < 16; ++c) s += b1[h*16+c]*att1[h*32+16+c]; }
    else if (i == 16){ for (int c = 0; c < 40; ++c) s += b2[c]*att2[c]; }
    else { for (int c = 0; c < 40; ++c) s += b2[c]*att2[40+c]; }
    consts[i] = s;
  }
}

// ---------------- GEMM1 (MFMA f16): h1 (fp8, row-major) + a1i/a1j (fp32) ----------------
__global__ __launch_bounds__(256) void k_gemm1(const float* __restrict__ x,
    const _Float16* __restrict__ Wh, const _Float16* __restrict__ attB,
    const float* __restrict__ b1, const float* __restrict__ consts,
    unsigned char* __restrict__ h1f8, float* __restrict__ a1i, float* __restrict__ a1j, int N){
  int wid  = (blockIdx.x*256 + threadIdx.x) >> 6;
  int lane = threadIdx.x & 63;
  int m0 = wid*16;
  if (m0 >= N) return;
  int col = lane & 15, quad = lane >> 4;
  const float* xr = x + (size_t)(m0+col)*128 + quad*8;
  f32x4 acc[9];
  #pragma unroll
  for (int t=0;t<9;t++){ acc[t][0]=0.f; acc[t][1]=0.f; acc[t][2]=0.f; acc[t][3]=0.f; }
  #pragma unroll
  for (int q=0;q<4;q++){
    float4 f0 = ((const float4*)(xr + q*32))[0];
    float4 f1 = ((const float4*)(xr + q*32))[1];
    f16x8 a;
    a[0]=(_Float16)f0.x; a[1]=(_Float16)f0.y; a[2]=(_Float16)f0.z; a[3]=(_Float16)f0.w;
    a[4]=(_Float16)f1.x; a[5]=(_Float16)f1.y; a[6]=(_Float16)f1.z; a[7]=(_Float16)f1.w;
    #pragma unroll
    for (int t=0;t<8;t++){
      const f16x8* Bp = (const f16x8*)(Wh + (size_t)(t*16+col)*128 + q*32 + quad*8);
      acc[t] = __builtin_amdgcn_mfma_f32_16x16x32_f16(a, *Bp, acc[t], 0,0,0);
    }
    const f16x8* Ap = (const f16x8*)(attB + (size_t)col*128 + q*32 + quad*8);
    acc[8] = __builtin_amdgcn_mfma_f32_16x16x32_f16(a, *Ap, acc[8], 0,0,0);
  }
  #pragma unroll
  for (int t=0;t<8;t++){
    int c = t*16 + col;
    float bb = b1[c];
    #pragma unroll
    for (int r=0;r<4;r++){
      h1f8[(size_t)(m0 + quad*4 + r)*128 + c] = f2fp8(acc[t][r] + bb);
    }
  }
  float hb = consts[col];
  #pragma unroll
  for (int r=0;r<4;r++){
    int node = m0 + quad*4 + r;
    float v = acc[8][r] + hb;
    if (col < 8) a1i[node*8 + col] = v;
    else         a1j[node*8 + (col-8)] = v;
  }
}

// ---------------- layer-1 fused softmax+aggregate: 4-stage pipelined fp8 gather ----------------
// one wave per node; quarter qt owns edge e+qt of each group of 4; lane ql owns
// channels 8*ql..8*ql+7 (uint2 of fp8), head = ql>>1. cs/aj ring: 16 edges ahead;
// feature u: 8 edges ahead via cs loaded 2 stages prior. fp32 accumulation.
__global__ __launch_bounds__(256) void k_agg1(const uint2* __restrict__ h1q,
    const float* __restrict__ a1i, const float* __restrict__ a1j,
    const int* __restrict__ rowstart, const int* __restrict__ csr,
    const float* __restrict__ bias, uint4* __restrict__ x2u4, int N){
  int lane = threadIdx.x & 63;
  int n = (blockIdx.x*blockDim.x + threadIdx.x) >> 6;
  if (n >= N) return;
  int ql = lane & 15, qt = lane >> 4;
  unsigned hd = (unsigned)ql >> 1;
  int rs = rowstart[n], re = rowstart[n+1];
  float ai2 = a1i[(unsigned)n*8u + hd];
  float a0=0.f,a1=0.f,a2=0.f,a3=0.f,a4=0.f,a5=0.f,a6=0.f,a7=0.f,den=0.f;
  {
    float w = (qt==0)? __expf(lrelu02(ai2 + a1j[(unsigned)n*8u + hd])) : 0.f;
    uint2 u = h1q[(unsigned)n*16u + (unsigned)ql];
    f32x2 f0 = __builtin_amdgcn_cvt_pk_f32_fp8((int)u.x, false);
    f32x2 f1 = __builtin_amdgcn_cvt_pk_f32_fp8((int)u.x, true);
    f32x2 f2 = __builtin_amdgcn_cvt_pk_f32_fp8((int)u.y, false);
    f32x2 f3 = __builtin_amdgcn_cvt_pk_f32_fp8((int)u.y, true);
    a0=w*f0[0]; a1=w*f0[1]; a2=w*f1[0]; a3=w*f1[1];
    a4=w*f2[0]; a5=w*f2[1]; a6=w*f3[0]; a7=w*f3[1];
    den = w;
  }
  int last = re - 1;
  if (rs < re){
    unsigned cs0 = (unsigned)csr[min(rs+0+qt,last)];
    unsigned cs1 = (unsigned)csr[min(rs+4+qt,last)];
    unsigned cs2 = (unsigned)csr[min(rs+8+qt,last)];
    unsigned cs3 = (unsigned)csr[min(rs+12+qt,last)];
    float aj0 = a1j[cs0*8u+hd], aj1 = a1j[cs1*8u+hd];
    float aj2 = a1j[cs2*8u+hd], aj3 = a1j[cs3*8u+hd];
    uint2 ua = h1q[(size_t)cs0*16u + (unsigned)ql];
    uint2 ub = h1q[(size_t)cs1*16u + (unsigned)ql];
    int e0 = rs;

#define AGG1_STAGE(AJ, CSPRE, CSSLOT, OFF)                                   \
    {                                                                        \
      uint2 uc = h1q[(size_t)CSPRE*16u + (unsigned)ql];                      \
      unsigned nc = (unsigned)csr[min(e0+OFF+16+qt, last)];                  \
      float w = (e0+OFF+qt < re)? __expf(lrelu02(ai2 + AJ)) : 0.f;           \
      den += w;                                                              \
      f32x2 g0 = __builtin_amdgcn_cvt_pk_f32_fp8((int)ua.x, false);          \
      f32x2 g1 = __builtin_amdgcn_cvt_pk_f32_fp8((int)ua.x, true);           \
      f32x2 g2 = __builtin_amdgcn_cvt_pk_f32_fp8((int)ua.y, false);          \
      f32x2 g3 = __builtin_amdgcn_cvt_pk_f32_fp8((int)ua.y, true);           \
      a0 += w*g0[0]; a1 += w*g0[1]; a2 += w*g1[0]; a3 += w*g1[1];            \
      a4 += w*g2[0]; a5 += w*g2[1]; a6 += w*g3[0]; a7 += w*g3[1];            \
      CSSLOT = nc; AJ = a1j[nc*8u + hd];                                     \
      ua = ub; ub = uc;                                                      \
    }

    while (e0 < re){
      AGG1_STAGE(aj0, cs2, cs0, 0)
      if (e0+4 >= re) break;
      AGG1_STAGE(aj1, cs3, cs1, 4)
      if (e0+8 >= re) break;
      AGG1_STAGE(aj2, cs0, cs2, 8)
      if (e0+12 >= re) break;
      AGG1_STAGE(aj3, cs1, cs3, 12)
      e0 += 16;
    }
#undef AGG1_STAGE
  }
  #pragma unroll
  for (int off = 16; off < 64; off <<= 1){
    den += __shfl_xor(den, off);
    a0 += __shfl_xor(a0, off); a1 += __shfl_xor(a1, off);
    a2 += __shfl_xor(a2, off); a3 += __shfl_xor(a3, off);
    a4 += __shfl_xor(a4, off); a5 += __shfl_xor(a5, off);
    a6 += __shfl_xor(a6, off); a7 += __shfl_xor(a7, off);
  }
  if (qt == 0){
    float invd = 1.f/(den + 1e-16f);
    const float4* b4 = (const float4*)(bias + 8*ql);
    float4 bl = b4[0], bh = b4[1];
    float o0=a0*invd+bl.x, o1=a1*invd+bl.y, o2=a2*invd+bl.z, o3=a3*invd+bl.w;
    float o4=a4*invd+bh.x, o5=a5*invd+bh.y, o6=a6*invd+bh.z, o7=a7*invd+bh.w;
    o0=(o0>0.f)?o0:(__expf(o0)-1.f); o1=(o1>0.f)?o1:(__expf(o1)-1.f);
    o2=(o2>0.f)?o2:(__expf(o2)-1.f); o3=(o3>0.f)?o3:(__expf(o3)-1.f);
    o4=(o4>0.f)?o4:(__expf(o4)-1.f); o5=(o5>0.f)?o5:(__expf(o5)-1.f);
    o6=(o6>0.f)?o6:(__expf(o6)-1.f); o7=(o7>0.f)?o7:(__expf(o7)-1.f);
    __half2 p0 = __floats2half2_rn(o0,o1), p1 = __floats2half2_rn(o2,o3);
    __half2 p2 = __floats2half2_rn(o4,o5), p3 = __floats2half2_rn(o6,o7);
    uint4 o;
    o.x = *(unsigned*)&p0; o.y = *(unsigned*)&p1; o.z = *(unsigned*)&p2; o.w = *(unsigned*)&p3;
    x2u4[(unsigned)n*16u + (unsigned)ql] = o;   // x2 stays f16 (MFMA A operand)
  }
}

// ---------------- GEMM2 (MFMA f16): h2 (fp8) + a2i/a2j ----------------
__global__ __launch_bounds__(256) void k_gemm2(const _Float16* __restrict__ xh,
    const _Float16* __restrict__ Wh, const _Float16* __restrict__ attB,
    const float* __restrict__ b2, const float* __restrict__ consts,
    unsigned char* __restrict__ h2f8, float* __restrict__ a2i, float* __restrict__ a2j, int N){
  int wid  = (blockIdx.x*256 + threadIdx.x) >> 6;
  int lane = threadIdx.x & 63;
  int m0 = wid*16;
  if (m0 >= N) return;
  int col = lane & 15, quad = lane >> 4;
  const f16x8* A8 = (const f16x8*)(xh + (size_t)(m0+col)*128 + quad*8);
  f32x4 acc[4];
  #pragma unroll
  for (int t=0;t<4;t++){ acc[t][0]=0.f; acc[t][1]=0.f; acc[t][2]=0.f; acc[t][3]=0.f; }
  #pragma unroll
  for (int q=0;q<4;q++){
    f16x8 a = A8[q*4];
    #pragma unroll
    for (int t=0;t<3;t++){
      const f16x8* Bp = (const f16x8*)(Wh + (size_t)(t*16+col)*128 + q*32 + quad*8);
      acc[t] = __builtin_amdgcn_mfma_f32_16x16x32_f16(a, *Bp, acc[t], 0,0,0);
    }
    const f16x8* Bp2 = (const f16x8*)(attB + (size_t)col*128 + q*32 + quad*8);
    acc[3] = __builtin_amdgcn_mfma_f32_16x16x32_f16(a, *Bp2, acc[3], 0,0,0);
  }
  #pragma unroll
  for (int t=0;t<3;t++){
    int c = t*16 + col;
    if (c < 40){
      float bb = b2[c];
      #pragma unroll
      for (int r=0;r<4;r++){
        h2f8[(size_t)(m0 + quad*4 + r)*40 + c] = f2fp8(acc[t][r] + bb);
      }
    }
  }
  if (col < 2){
    float cc = consts[16 + col];
    #pragma unroll
    for (int r=0;r<4;r++){
      int node = m0 + quad*4 + r;
      if (col == 0) a2i[node] = acc[3][r] + cc;
      else          a2j[node] = acc[3][r] + cc;
    }
  }
}

// ---------------- layer-2 fused softmax+aggregate + log_softmax ----------------
// FOUR nodes per wave (quarters); lanes ql<10 own 4 channels (uint of fp8).
// Per-quarter divergent edge loop, 4-stage pipeline: cs/aj ring 4 ahead,
// feature u prefetched 2 stages ahead. fp32 accumulation.
__global__ __launch_bounds__(256) void k_agg2(const unsigned* __restrict__ h2u,
    const float* __restrict__ a2i, const float* __restrict__ a2j,
    const int* __restrict__ rowstart, const int* __restrict__ csr,
    const float* __restrict__ bias, float* __restrict__ out, int N){
  int lane = threadIdx.x & 63;
  int wid = (blockIdx.x*blockDim.x + threadIdx.x) >> 6;
  int qt = lane >> 4, ql = lane & 15;
  int n = wid*4 + qt;
  if (n >= N) return;
  bool act = ql < 10;
  unsigned cl = act ? (unsigned)ql : 0u;
  int rs = rowstart[n], re = rowstart[n+1];
  float ai = a2i[n];
  float wself = __expf(lrelu02(ai + a2j[n]));
  float a0,a1,a2,a3,den;
  {
    unsigned u = h2u[(unsigned)n*10u + cl];
    f32x2 f0 = __builtin_amdgcn_cvt_pk_f32_fp8((int)u, false);
    f32x2 f1 = __builtin_amdgcn_cvt_pk_f32_fp8((int)u, true);
    a0 = wself*f0[0]; a1 = wself*f0[1]; a2 = wself*f1[0]; a3 = wself*f1[1];
    den = wself;
  }
  if (rs < re){
    int last = re - 1;
    unsigned cs0 = (unsigned)csr[min(rs+0,last)];
    unsigned cs1 = (unsigned)csr[min(rs+1,last)];
    unsigned cs2 = (unsigned)csr[min(rs+2,last)];
    unsigned cs3 = (unsigned)csr[min(rs+3,last)];
    float aj0 = a2j[cs0], aj1 = a2j[cs1], aj2 = a2j[cs2], aj3 = a2j[cs3];
    unsigned ua = h2u[cs0*10u + cl];
    unsigned ub = h2u[cs1*10u + cl];
    int e0 = rs;

#define AGG2_STAGE(AJ, CSPRE, CSSLOT, OFF)                                   \
    {                                                                        \
      unsigned uc = h2u[CSPRE*10u + cl];                                     \
      unsigned nc = (unsigned)csr[min(e0+OFF+4, last)];                      \
      float w = (e0+OFF < re)? __expf(lrelu02(ai + AJ)) : 0.f;               \
      den += w;                                                              \
      f32x2 g0 = __builtin_amdgcn_cvt_pk_f32_fp8((int)ua, false);            \
      f32x2 g1 = __builtin_amdgcn_cvt_pk_f32_fp8((int)ua, true);             \
      a0 += w*g0[0]; a1 += w*g0[1]; a2 += w*g1[0]; a3 += w*g1[1];            \
      CSSLOT = nc; AJ = a2j[nc];                                             \
      ua = ub; ub = uc;                                                      \
    }

    while (e0 < re){
      AGG2_STAGE(aj0, cs2, cs0, 0)
      AGG2_STAGE(aj1, cs3, cs1, 1)
      AGG2_STAGE(aj2, cs0, cs2, 2)
      AGG2_STAGE(aj3, cs1, cs3, 3)
      e0 += 4;
    }
#undef AGG2_STAGE
  }
  float invd = 1.f/(den + 1e-16f);
  const float4* b4 = (const float4*)(bias + 4*cl);
  float4 bb = b4[0];
  float v0 = a0*invd + bb.x, v1 = a1*invd + bb.y;
  float v2 = a2*invd + bb.z, v3 = a3*invd + bb.w;
  float mv = act ? fmaxf(fmaxf(v0,v1), fmaxf(v2,v3)) : -INFINITY;
  #pragma unroll
  for (int off = 1; off < 16; off <<= 1) mv = fmaxf(mv, __shfl_xor(mv, off));
  float se = act ? (__expf(v0-mv)+__expf(v1-mv)+__expf(v2-mv)+__expf(v3-mv)) : 0.f;
  #pragma unroll
  for (int off = 1; off < 16; off <<= 1) se += __shfl_xor(se, off);
  float ls = __logf(se);
  if (act){
    float4 o = make_float4(v0-mv-ls, v1-mv-ls, v2-mv-ls, v3-mv-ls);
    ((float4*)out)[(unsigned)n*10u + cl] = o;
  }
}

extern "C" void kernel_launch(void* const* d_in, const int* in_sizes, int n_in,
                              void* d_out, int out_size, void* d_ws, size_t ws_size,
                              hipStream_t stream){
  const float* x     = (const float*)d_in[0];
  const int*   ei    = (const int*)  d_in[1];
  const float* W1    = (const float*)d_in[2];
  const float* b1    = (const float*)d_in[3];
  const float* att1  = (const float*)d_in[4];
  const float* bias1 = (const float*)d_in[5];
  const float* W2    = (const float*)d_in[6];
  const float* b2    = (const float*)d_in[7];
  const float* att2  = (const float*)d_in[8];
  const float* bias2 = (const float*)d_in[9];
  int N = in_sizes[0] / 128;
  int E = in_sizes[1] / 2;
  const int* src = ei;
  const int* dst = ei + E;

  char* ws = (char*)d_ws;
  size_t off = 0;
  auto alloc = [&](size_t bytes)->char*{
    char* p = ws + off; off += (bytes + 255) & ~(size_t)255; return p;
  };
  unsigned char* h1f8 = (unsigned char*)alloc((size_t)N*128);   // fp8 row-major
  _Float16*      x2h  = (_Float16*)alloc((size_t)N*128*2);      // f16 (MFMA A)
  unsigned char* h2f8 = (unsigned char*)alloc((size_t)N*40);    // fp8 row-major
  float* a1i  = (float*)alloc((size_t)N*8*4);
  float* a1j  = (float*)alloc((size_t)N*8*4);
  float* a2i  = (float*)alloc((size_t)N*4);
  float* a2j  = (float*)alloc((size_t)N*4);
  _Float16* W1h   = (_Float16*)alloc(16384*2);
  _Float16* W2h   = (_Float16*)alloc(6144*2);
  _Float16* attB1 = (_Float16*)alloc(2048*2);
  _Float16* attB2 = (_Float16*)alloc(2048*2);
  float* consts = (float*)alloc(18*4);
  int*   deg  = (int*)  alloc((size_t)N*4);
  int*   rank = (int*)  alloc((size_t)E*4);
  int*   rowst= (int*)  alloc((size_t)(N+1)*4);
  int*   csr  = (int*)  alloc((size_t)E*4);
  int*   bsum = (int*)  alloc(4096);

  hipMemsetAsync(deg, 0, (size_t)N*4, stream);
  int nblk = (N + 1023)/1024;
  k_rank<<<(E+255)/256, 256, 0, stream>>>(dst, deg, rank, E);
  k_scanA<<<nblk, 256, 0, stream>>>(deg, rowst, bsum, N);
  k_scanB<<<1, 128, 0, stream>>>(bsum, nblk);
  k_scanC<<<(N+255)/256, 256, 0, stream>>>(rowst, bsum, N, E);
  k_fillx<<<1024, 256, 0, stream>>>(src, dst, rank, rowst, csr, E, N);
  k_prep<<<105, 256, 0, stream>>>(W1, b1, att1, W2, b2, att2, W1h, W2h, attB1, attB2, consts);

  int gblk = ((N+15)/16 + 3)/4;  // 4 waves/block, 16 nodes/wave
  k_gemm1<<<gblk, 256, 0, stream>>>(x, W1h, attB1, b1, consts, h1f8, a1i, a1j, N);
  k_agg1<<<(N*64+255)/256, 256, 0, stream>>>((const uint2*)h1f8, a1i, a1j, rowst, csr, bias1, (uint4*)x2h, N);

  k_gemm2<<<gblk, 256, 0, stream>>>(x2h, W2h, attB2, b2, consts, h2f8, a2i, a2j, N);
  k_agg2<<<(N+15)/16, 256, 0, stream>>>((const unsigned*)h2f8, a2i, a2j, rowst, csr, bias2, (float*)d_out, N);
}